// Round 5
// baseline (5977.153 us; speedup 1.0000x reference)
//
#include <hip/hip_runtime.h>

// SPINN stack-encoder v5: direct-global operands (no LDS staging, no per-chunk
// syncthreads), LDS-resident weights read as wave-broadcast b128, 8-wave MLP
// hides post-fence L3 refill latency. 2 grid barriers/step (monotonic relaxed
// hierarchical barrier).

constexpr int NB  = 128;
constexpr int LL  = 32;
constexpr int TT  = 63;
constexpr int NWG = 256;
constexpr int NTH = 512;
constexpr int SROWS = 64;

struct Params {
  const float* seq; const int* trans;
  const float* Wx[4];                // i,o,f,u ; Wx[2]==W_o (ref bug kept)
  const float* Ul[4]; const float* Ur[4];
  const float* bias[4];              // b_i, b_o, b_f, b_u
  const float* tWih; const float* tWhh; const float* tbih; const float* tbhh;
  const float* th0; const float* tc0;
  float* stack; float* tg;
  unsigned* bm;
  float* out;
};

__device__ __forceinline__ float sigm(float x) { return 1.0f / (1.0f + __expf(-x)); }
__device__ __forceinline__ float tanh_f(float x) {
  x = fminf(fmaxf(x, -15.0f), 15.0f);
  float e = __expf(2.0f * x);
  return (e - 1.0f) / (e + 1.0f);
}

// Monotonic hierarchical grid barrier (relaxed atomics, one fence each side).
__device__ __forceinline__ void gsync(unsigned* bm, unsigned gen, int w) {
  __syncthreads();
  if (threadIdx.x == 0) {
    __threadfence();                                   // release
    unsigned* c    = bm + (w & 7) * 32;
    unsigned* root = bm + 320;
    unsigned* bar  = bm + 352;
    unsigned a = __hip_atomic_fetch_add(c, 1u, __ATOMIC_RELAXED,
                                        __HIP_MEMORY_SCOPE_AGENT) + 1u;
    if (a == gen * 32u) {
      unsigned r = __hip_atomic_fetch_add(root, 1u, __ATOMIC_RELAXED,
                                          __HIP_MEMORY_SCOPE_AGENT) + 1u;
      if (r == gen * 8u) {
        __hip_atomic_store(bar, gen, __ATOMIC_RELAXED, __HIP_MEMORY_SCOPE_AGENT);
      }
    }
    while (__hip_atomic_load(bar, __ATOMIC_RELAXED, __HIP_MEMORY_SCOPE_AGENT) < gen) {
      __builtin_amdgcn_s_sleep(1);
    }
    __threadfence();                                   // acquire
  }
  __syncthreads();
}

__launch_bounds__(NTH)
__global__ void spinn_kernel(Params p) {
  const int w = blockIdx.x;
  const int t = threadIdx.x;

  __shared__ float wTree[8][1024];   // row g*2+nc; k<512 = Ul, k>=512 = Ur
  __shared__ float wTrk[1600];       // col w: [0,512)buf [512,1024)sp1 [1024,1536)sp2 [1536,1600)th
  __shared__ float wX[8][64];
  __shared__ float tbsum[256];
  __shared__ float biasS[8];
  __shared__ float th2s[128][68];    // tracking h state, all b
  __shared__ float accS[4][8][128];  // [q][col][b] tree partials
  __shared__ float accT[16][128];    // tracking partials
  __shared__ float preS[128][9];
  __shared__ unsigned char qstk[128][64];
  __shared__ short qln[128];
  __shared__ short bpt[128];
  __shared__ unsigned char sp1s[128], sp2s[128], reds[128], bufs[128];
  __shared__ int anyred;

  const int n0 = w * 2;                                     // owned h-cols
  const int q  = __builtin_amdgcn_readfirstlane(t >> 7);    // 0..3 wave-uniform
  const int cp = (t >> 5) & 3;
  const int bg = t & 31;
  const int bb = t & 127;
  const int g16 = q * 4 + cp;

  // ---- prologue: weights -> LDS (fetched once; LDS survives fences)
  for (int i = t; i < 2048; i += NTH) {          // wTree: 8 x 256 float4
    int r = i >> 8, kf = i & 255;
    int g = r >> 1, nc = r & 1;
    int k = kf * 4;
    float4 v;
    if (k < 512) v = *(const float4*)(p.Ul[g] + (size_t)(n0 + nc) * 512 + k);
    else         v = *(const float4*)(p.Ur[g] + (size_t)(n0 + nc) * 512 + (k - 512));
    *(float4*)&wTree[r][k] = v;
  }
  for (int i = t; i < 400; i += NTH) {           // wTrk: 400 float4
    int k = i * 4;
    float4 v;
    if (k < 1536) v = *(const float4*)(p.tWih + (size_t)w * 1536 + k);
    else          v = *(const float4*)(p.tWhh + (size_t)w * 64 + (k - 1536));
    *(float4*)&wTrk[k] = v;
  }
  for (int i = t; i < 128; i += NTH) {           // wX: 8 x 16 float4
    int r = i >> 4, jf = i & 15;
    int g = r >> 1, nc = r & 1;
    *(float4*)&wX[r][jf * 4] = *(const float4*)(p.Wx[g] + (size_t)(n0 + nc) * 64 + jf * 4);
  }
  if (t < 256) tbsum[t] = p.tbih[t] + p.tbhh[t];
  if (t < 8) biasS[t] = p.bias[t >> 1][n0 + (t & 1)];
  for (int i = t; i < 8192; i += NTH) th2s[i >> 6][i & 63] = p.th0[i];
  float tcr[16];                                  // tc state in regs: (bb, q)
  #pragma unroll
  for (int jj = 0; jj < 16; ++jj) tcr[jj] = p.tc0[bb * 64 + q * 16 + jj];
  { int i = w * NTH + t;                          // zero stack row 0
    p.stack[(size_t)(i >> 10) * (SROWS * 1024) + (i & 1023)] = 0.0f; }
  if (t < NB) { qln[t] = 0; bpt[t] = 0; }
  unsigned gen = 0;
  gsync(p.bm, ++gen, w);

  for (int step = 1; step <= TT; ++step) {
    // ---- schedule sim (redundant per WG)
    if (t < NB) {
      int b2 = t;
      int mask = p.trans[b2 * TT + (step - 1)];
      int qn = qln[b2];
      int s1 = (qn >= 1) ? qstk[b2][qn - 1] : 0;
      int s2 = (qn >= 2) ? qstk[b2][qn - 2] : 0;
      int rd = (mask == 1);
      sp1s[b2] = (unsigned char)s1;
      sp2s[b2] = (unsigned char)s2;
      reds[b2] = (unsigned char)rd;
      int bp = bpt[b2];
      bufs[b2] = (unsigned char)((bp < LL) ? bp : LL);
      int qn2 = rd ? (qn - 2) : qn;
      qstk[b2][qn2] = (unsigned char)step;
      qln[b2] = (short)(qn2 + 1);
      bpt[b2] = (short)(bp + (rd ? 0 : 1));
    }
    __syncthreads();
    if (t == 0) { int a = 0; for (int b2 = 0; b2 < NB; ++b2) a |= reds[b2]; anyred = a; }
    __syncthreads();

    // ================= SEG 1: direct-global operands =================
    // Tree (reduce steps): thread (q,cp,bg): cols {cp*2,cp*2+1}, K-slice q*256,
    // b rows {bg, bg+32, bg+64, bg+96}.
    if (anyred) {
      const float* ops[4];
      #pragma unroll
      for (int bi = 0; bi < 4; ++bi) {
        int row = bg + bi * 32;
        int sp = (q < 2) ? sp1s[row] : sp2s[row];
        ops[bi] = p.stack + ((size_t)row * SROWS + sp) * 1024 + (q & 1) * 256;
      }
      float a00 = 0.f, a01 = 0.f, a02 = 0.f, a03 = 0.f;
      float a10 = 0.f, a11 = 0.f, a12 = 0.f, a13 = 0.f;
      const float* wt0 = &wTree[cp * 2    ][q * 256];
      const float* wt1 = &wTree[cp * 2 + 1][q * 256];
      #pragma unroll 4
      for (int kf = 0; kf < 64; ++kf) {
        float4 w0 = *(const float4*)(wt0 + kf * 4);      // LDS broadcast
        float4 w1 = *(const float4*)(wt1 + kf * 4);      // LDS broadcast
        float4 v0 = *(const float4*)(ops[0] + kf * 4);
        float4 v1 = *(const float4*)(ops[1] + kf * 4);
        float4 v2 = *(const float4*)(ops[2] + kf * 4);
        float4 v3 = *(const float4*)(ops[3] + kf * 4);
        a00 += w0.x*v0.x + w0.y*v0.y + w0.z*v0.z + w0.w*v0.w;
        a01 += w0.x*v1.x + w0.y*v1.y + w0.z*v1.z + w0.w*v1.w;
        a02 += w0.x*v2.x + w0.y*v2.y + w0.z*v2.z + w0.w*v2.w;
        a03 += w0.x*v3.x + w0.y*v3.y + w0.z*v3.z + w0.w*v3.w;
        a10 += w1.x*v0.x + w1.y*v0.y + w1.z*v0.z + w1.w*v0.w;
        a11 += w1.x*v1.x + w1.y*v1.y + w1.z*v1.z + w1.w*v1.w;
        a12 += w1.x*v2.x + w1.y*v2.y + w1.z*v2.z + w1.w*v2.w;
        a13 += w1.x*v3.x + w1.y*v3.y + w1.z*v3.z + w1.w*v3.w;
      }
      accS[q][cp * 2    ][bg     ] = a00;
      accS[q][cp * 2    ][bg + 32] = a01;
      accS[q][cp * 2    ][bg + 64] = a02;
      accS[q][cp * 2    ][bg + 96] = a03;
      accS[q][cp * 2 + 1][bg     ] = a10;
      accS[q][cp * 2 + 1][bg + 32] = a11;
      accS[q][cp * 2 + 1][bg + 64] = a12;
      accS[q][cp * 2 + 1][bg + 96] = a13;
    }
    // Tracking (every step): region q (0:buf 1:sp1 2:sp2 3:th), sub-slice cp.
    {
      float tacc[4] = {0.f, 0.f, 0.f, 0.f};
      if (q < 3) {
        const int ko = cp * 128;
        const float* twb = &wTrk[q * 512 + ko];
        #pragma unroll
        for (int bi = 0; bi < 4; ++bi) {
          int row = bg + bi * 32;
          const float* src = nullptr;
          if (q == 0) { int bx = bufs[row];
                        if (bx < LL) src = p.seq + ((size_t)row * LL + bx) * 1024 + ko; }
          else if (q == 1) src = p.stack + ((size_t)row * SROWS + sp1s[row]) * 1024 + ko;
          else             src = p.stack + ((size_t)row * SROWS + sp2s[row]) * 1024 + ko;
          if (src) {
            float a = 0.f;
            #pragma unroll 8
            for (int kf = 0; kf < 32; ++kf) {
              float4 v  = *(const float4*)(src + kf * 4);
              float4 tw = *(const float4*)(twb + kf * 4);   // LDS broadcast
              a += v.x*tw.x + v.y*tw.y + v.z*tw.z + v.w*tw.w;
            }
            tacc[bi] = a;
          }
        }
      } else {
        const int j0 = cp * 16;
        #pragma unroll
        for (int bi = 0; bi < 4; ++bi) {
          int row = bg + bi * 32;
          float a = 0.f;
          #pragma unroll
          for (int jf = 0; jf < 4; ++jf) {
            float4 tw = *(const float4*)&wTrk[1536 + j0 + jf * 4];
            float4 th = *(const float4*)&th2s[row][j0 + jf * 4];
            a += th.x*tw.x + th.y*tw.y + th.z*tw.z + th.w*tw.w;
          }
          tacc[bi] = a;
        }
      }
      #pragma unroll
      for (int bi = 0; bi < 4; ++bi) accT[g16][bg + bi * 32] = tacc[bi];
    }
    __syncthreads();
    if (t < NB) {
      float sm = 0.f;
      #pragma unroll
      for (int si = 0; si < 16; ++si) sm += accT[si][t];
      p.tg[(size_t)w * NB + t] = sm;                       // [c][b], coalesced
    }

    gsync(p.bm, ++gen, w);

    // ================= SEG 2 =================
    float clv = 0.f, crv = 0.f, bhv = 0.f, bcv = 0.f;
    const int bF = t & 127, nF = (t >> 7) & 1;
    if (t < 256) {
      clv = p.stack[((size_t)bF * SROWS + sp1s[bF]) * 1024 + 512 + n0 + nF];
      crv = p.stack[((size_t)bF * SROWS + sp2s[bF]) * 1024 + 512 + n0 + nF];
      int bx = bufs[bF];
      if (bx < LL) {
        bhv = p.seq[((size_t)bF * LL + bx) * 1024 + n0 + nF];
        bcv = p.seq[((size_t)bF * LL + bx) * 1024 + 512 + n0 + nF];
      }
    }
    // tracking state update: thread (bb, q) owns tc[16] in regs
    {
      #pragma unroll
      for (int jj = 0; jj < 16; ++jj) {
        int j = q * 16 + jj;
        float gi = p.tg[(size_t)j * NB + bb]         + tbsum[j];
        float gf = p.tg[(size_t)(64 + j) * NB + bb]  + tbsum[64 + j];
        float gg = p.tg[(size_t)(128 + j) * NB + bb] + tbsum[128 + j];
        float go = p.tg[(size_t)(192 + j) * NB + bb] + tbsum[192 + j];
        float c2 = sigm(gf) * tcr[jj] + sigm(gi) * tanh_f(gg);
        float h2 = sigm(go) * tanh_f(c2);
        th2s[bb][j] = h2;
        tcr[jj] = c2;
      }
    }
    __syncthreads();
    if (anyred) {
      const int r0s = q * 2, r1s = r0s + 1;        // gate q, cols n0 / n0+1
      float x0 = 0.f, x1 = 0.f;
      #pragma unroll 4
      for (int j4 = 0; j4 < 64; j4 += 4) {
        float4 xv = *(const float4*)&th2s[bb][j4];
        float4 wa = *(const float4*)&wX[r0s][j4];
        float4 wb = *(const float4*)&wX[r1s][j4];
        x0 += xv.x*wa.x + xv.y*wa.y + xv.z*wa.z + xv.w*wa.w;
        x1 += xv.x*wb.x + xv.y*wb.y + xv.z*wb.z + xv.w*wb.w;
      }
      preS[bb][r0s] = accS[0][r0s][bb] + accS[1][r0s][bb] + accS[2][r0s][bb]
                    + accS[3][r0s][bb] + x0 + biasS[r0s];
      preS[bb][r1s] = accS[0][r1s][bb] + accS[1][r1s][bb] + accS[2][r1s][bb]
                    + accS[3][r1s][bb] + x1 + biasS[r1s];
    }
    __syncthreads();
    if (t < 256) {
      float h, c;
      if (reds[bF]) {
        float iv = sigm(preS[bF][0 + nF]);
        float ov = sigm(preS[bF][2 + nF]);
        float fv = sigm(preS[bF][4 + nF]);
        float uv = tanh_f(preS[bF][6 + nF]);
        c = iv * uv + fv * (clv + crv);
        h = ov * tanh_f(c);
      } else { h = bhv; c = bcv; }
      float* sr = p.stack + ((size_t)bF * SROWS + step) * 1024 + n0 + nF;
      sr[0] = h;
      sr[512] = c;
      if (step == TT) p.out[(size_t)bF * 512 + n0 + nF] = h;
    }
    gsync(p.bm, ++gen, w);
  }
}

extern "C" void kernel_launch(void* const* d_in, const int* in_sizes, int n_in,
                              void* d_out, int out_size, void* d_ws, size_t ws_size,
                              hipStream_t stream) {
  Params p;
  p.seq   = (const float*)d_in[0];
  p.trans = (const int*)d_in[1];
  p.Wx[0] = (const float*)d_in[2];   // W_i
  p.Wx[1] = (const float*)d_in[4];   // W_o
  p.Wx[2] = (const float*)d_in[4];   // W_o  (ref bug: f-gate uses W_o)
  p.Wx[3] = (const float*)d_in[5];   // W_u
  p.Ul[0] = (const float*)d_in[6];  p.Ur[0] = (const float*)d_in[7];    // i
  p.Ul[1] = (const float*)d_in[10]; p.Ur[1] = (const float*)d_in[11];   // o
  p.Ul[2] = (const float*)d_in[8];  p.Ur[2] = (const float*)d_in[9];    // f
  p.Ul[3] = (const float*)d_in[12]; p.Ur[3] = (const float*)d_in[13];   // u
  p.bias[0] = (const float*)d_in[14];  // b_i
  p.bias[1] = (const float*)d_in[16];  // b_o
  p.bias[2] = (const float*)d_in[15];  // b_f
  p.bias[3] = (const float*)d_in[17];  // b_u
  p.tWih = (const float*)d_in[18];
  p.tWhh = (const float*)d_in[19];
  p.tbih = (const float*)d_in[20];
  p.tbhh = (const float*)d_in[21];
  p.th0  = (const float*)d_in[22];
  p.tc0  = (const float*)d_in[23];

  float* ws = (float*)d_ws;
  size_t off = 0;
  p.stack = ws + off; off += (size_t)NB * SROWS * 1024;  // 32 MB
  p.tg    = ws + off; off += (size_t)256 * NB;           // 128 KB
  unsigned* barmem = (unsigned*)(ws + off); off += 512;
  if (off * sizeof(float) > ws_size) return;
  p.bm  = barmem;
  p.out = (float*)d_out;

  hipMemsetAsync(barmem, 0, 512 * sizeof(unsigned), stream);

  void* args[] = { &p };
  hipError_t e = hipLaunchCooperativeKernel((void*)spinn_kernel, dim3(NWG), dim3(NTH),
                                            args, 0, stream);
  if (e != hipSuccess) {
    (void)hipGetLastError();
    spinn_kernel<<<dim3(NWG), dim3(NTH), 0, stream>>>(p);
  }
}

// Round 6
// 1667.910 us; speedup vs baseline: 3.5836x; 3.5836x over previous
//
#include <hip/hip_runtime.h>

// SPINN v6: fence-free coherence. Cross-WG data (stack rows, tg) exchanged via
// agent-scope relaxed atomics (sc1 -> Infinity Cache coherence point); grid
// barrier has release-only fence (writeback, no invalidate) so L1/L2 stay warm
// across steps (weights/seq cached). 2D partition: 32 col-groups x 8 b-groups;
// WG owns 16 b-rows x 16 H-cols (4 gates, full K) + 8 tracking outs (K=1600).
// Operands staged once/step into LDS (64KB coherent reads), no hpre roundtrip.

constexpr int NB  = 128;
constexpr int LL  = 32;
constexpr int TT  = 63;
constexpr int NWG = 256;
constexpr int NTH = 512;
constexpr int SROWS = 64;
constexpr int BPG = 16;            // batch rows per b-group

struct Params {
  const float* seq; const int* trans;
  const float* Wx[4];              // i,o,f,u ; Wx[2]==W_o (ref bug kept)
  const float* Ul[4]; const float* Ur[4];
  const float* bias[4];            // b_i, b_o, b_f, b_u
  const float* tWih; const float* tWhh; const float* tbih; const float* tbhh;
  const float* th0; const float* tc0;
  float* stack; float* tg;
  unsigned* bm;
  float* out;
};

__device__ __forceinline__ float sigm(float x) { return 1.0f / (1.0f + __expf(-x)); }
__device__ __forceinline__ float tanh_f(float x) {
  x = fminf(fmaxf(x, -15.0f), 15.0f);
  float e = __expf(2.0f * x);
  return (e - 1.0f) / (e + 1.0f);
}
__device__ __forceinline__ float cohLoad(const float* a) {
  return __hip_atomic_load(const_cast<float*>(a), __ATOMIC_RELAXED, __HIP_MEMORY_SCOPE_AGENT);
}
__device__ __forceinline__ void cohStore(float* a, float v) {
  __hip_atomic_store(a, v, __ATOMIC_RELAXED, __HIP_MEMORY_SCOPE_AGENT);
}

// Grid barrier: monotonic relaxed counters; release-only fence (L2 writeback,
// NO invalidate). sc1 data stores are drained (vmcnt) before arrival.
__device__ __forceinline__ void gsync(unsigned* bm, unsigned gen, int w) {
  asm volatile("s_waitcnt vmcnt(0)" ::: "memory");
  __syncthreads();
  if (threadIdx.x == 0) {
    __builtin_amdgcn_fence(__ATOMIC_RELEASE, "agent");   // wb only
    unsigned* c    = bm + (w & 7) * 32;
    unsigned* root = bm + 320;
    unsigned* bar  = bm + 352;
    unsigned a = __hip_atomic_fetch_add(c, 1u, __ATOMIC_RELAXED,
                                        __HIP_MEMORY_SCOPE_AGENT) + 1u;
    if (a == gen * 32u) {
      unsigned r = __hip_atomic_fetch_add(root, 1u, __ATOMIC_RELAXED,
                                          __HIP_MEMORY_SCOPE_AGENT) + 1u;
      if (r == gen * 8u)
        __hip_atomic_store(bar, gen, __ATOMIC_RELAXED, __HIP_MEMORY_SCOPE_AGENT);
    }
    while (__hip_atomic_load(bar, __ATOMIC_RELAXED, __HIP_MEMORY_SCOPE_AGENT) < gen) {
      __builtin_amdgcn_s_sleep(1);
    }
  }
  __syncthreads();
}

__launch_bounds__(NTH)
__global__ void spinn_kernel(Params p) {
  const int w = blockIdx.x;
  const int t = threadIdx.x;
  const int cg  = w & 31;            // col-group: H-cols [cg*16, cg*16+16)
  const int bgp = w >> 5;            // b-group: rows [bgp*16, bgp*16+16)
  const int b0  = bgp * BPG;
  const int nc0 = cg * 16;
  const int o0  = cg * 8;            // tracking outs [o0, o0+8)

  __shared__ float opAll[16][1540];  // [b][ buf(512) | sp1h(512) | sp2h(512) ]
  __shared__ float th2s[16][68];
  __shared__ float tc2s[16][68];
  __shared__ float wXs[64][64];      // cc = g*16+n
  __shared__ float accS[4][64][17];  // [kth][cc][b]
  __shared__ float xS[64][17];
  __shared__ float accT[8][8][17];   // [kth][o][b]
  __shared__ float tbsum[256];
  __shared__ float biasS[4][16];
  __shared__ unsigned char sp1t[TT + 1][16], sp2t[TT + 1][16];
  __shared__ unsigned char buft[TT + 1][16], redt[TT + 1][16];
  __shared__ int anyredt[TT + 1];
  __shared__ unsigned char qstkS[16][40];

  // ---- prologue (all cached normal loads; nothing cross-WG yet)
  if (t < 256) tbsum[t] = p.tbih[t] + p.tbhh[t];
  if (t < 64) biasS[t >> 4][t & 15] = p.bias[t >> 4][nc0 + (t & 15)];
  for (int i = t; i < 4096; i += NTH) {
    int cc = i >> 6, j = i & 63;
    wXs[cc][j] = p.Wx[cc >> 4][(size_t)(nc0 + (cc & 15)) * 64 + j];
  }
  for (int i = t; i < 1024; i += NTH) {
    int b = i >> 6, j = i & 63;
    th2s[b][j] = p.th0[(size_t)(b0 + b) * 64 + j];
    tc2s[b][j] = p.tc0[(size_t)(b0 + b) * 64 + j];
  }
  if (t < 16) {                       // full-schedule sim for our 16 b
    int bl = t, qn = 0, bp = 0;
    for (int s = 1; s <= TT; ++s) {
      int mask = p.trans[(size_t)(b0 + bl) * TT + (s - 1)];
      int s1 = (qn >= 1) ? qstkS[bl][qn - 1] : 0;
      int s2 = (qn >= 2) ? qstkS[bl][qn - 2] : 0;
      int rd = (mask == 1);
      sp1t[s][bl] = (unsigned char)s1;
      sp2t[s][bl] = (unsigned char)s2;
      redt[s][bl] = (unsigned char)rd;
      buft[s][bl] = (unsigned char)((bp < LL) ? bp : LL);
      int qn2 = rd ? (qn - 2) : qn;
      qstkS[bl][qn2] = (unsigned char)s;
      qn = qn2 + 1;
      bp += rd ? 0 : 1;
    }
  }
  __syncthreads();
  if (t == 0) {
    for (int s = 1; s <= TT; ++s) {
      int a = 0;
      for (int bl = 0; bl < 16; ++bl) a |= redt[s][bl];
      anyredt[s] = a;
    }
  }
  unsigned gen = 0;
  gsync(p.bm, ++gen, w);             // flushes any dirty poison to IC
  // zero stack row 0 of our 16 b (coherent; after the flush barrier)
  for (int i = t; i < BPG * 1024; i += NTH)
    cohStore(p.stack + ((size_t)(b0 + (i >> 10)) * SROWS) * 1024 + (i & 1023), 0.0f);
  gsync(p.bm, ++gen, w);

  for (int step = 1; step <= TT; ++step) {
    const int anyred = anyredt[step];

    // ---- stage operands: 16 rows x {buf, sp1_h, sp2_h}; k = t (0..511)
    #pragma unroll 4
    for (int r = 0; r < 16; ++r) {
      int s1 = sp1t[step][r], s2 = sp2t[step][r], bx = buft[step][r];
      float v1 = cohLoad(p.stack + ((size_t)(b0 + r) * SROWS + s1) * 1024 + t);
      float v2 = cohLoad(p.stack + ((size_t)(b0 + r) * SROWS + s2) * 1024 + t);
      float vb = (bx < LL) ? p.seq[((size_t)(b0 + r) * LL + bx) * 1024 + t] : 0.0f;
      opAll[r][512 + t]  = v1;
      opAll[r][1024 + t] = v2;
      opAll[r][t]        = vb;
    }
    __syncthreads();

    // ---- compute: tree on t<256 (reduce steps), tracking on t>=256
    if (t < 256) {
      if (anyred) {
        const int bth = t & 3, cth = (t >> 2) & 15, kth = t >> 6;
        const int g = cth >> 2;
        const float* Um = (kth < 2) ? p.Ul[g] : p.Ur[g];
        const int koff = (kth & 1) * 256;
        const int nb = nc0 + (cth & 3) * 4;
        const float* w0 = Um + (size_t)(nb    ) * 512 + koff;
        const float* w1 = Um + (size_t)(nb + 1) * 512 + koff;
        const float* w2 = Um + (size_t)(nb + 2) * 512 + koff;
        const float* w3 = Um + (size_t)(nb + 3) * 512 + koff;
        const int ob = ((kth < 2) ? 512 : 1024) + koff;
        float acc[4][4];
        #pragma unroll
        for (int i = 0; i < 4; ++i)
          #pragma unroll
          for (int j = 0; j < 4; ++j) acc[i][j] = 0.0f;
        #pragma unroll 2
        for (int k4 = 0; k4 < 64; ++k4) {
          const int kk = k4 * 4;
          float4 wv0 = *(const float4*)(w0 + kk);
          float4 wv1 = *(const float4*)(w1 + kk);
          float4 wv2 = *(const float4*)(w2 + kk);
          float4 wv3 = *(const float4*)(w3 + kk);
          #pragma unroll
          for (int bi = 0; bi < 4; ++bi) {
            float4 ov = *(const float4*)&opAll[bi * 4 + bth][ob + kk];
            acc[0][bi] += wv0.x*ov.x + wv0.y*ov.y + wv0.z*ov.z + wv0.w*ov.w;
            acc[1][bi] += wv1.x*ov.x + wv1.y*ov.y + wv1.z*ov.z + wv1.w*ov.w;
            acc[2][bi] += wv2.x*ov.x + wv2.y*ov.y + wv2.z*ov.z + wv2.w*ov.w;
            acc[3][bi] += wv3.x*ov.x + wv3.y*ov.y + wv3.z*ov.z + wv3.w*ov.w;
          }
        }
        const int cc0 = cth * 4;
        #pragma unroll
        for (int ci = 0; ci < 4; ++ci)
          #pragma unroll
          for (int bi = 0; bi < 4; ++bi)
            accS[kth][cc0 + ci][bi * 4 + bth] = acc[ci][bi];
      }
    } else {
      const int tt = t - 256;
      const int oth = tt & 7, bth4 = (tt >> 3) & 3, kth = tt >> 5;  // 8x4x8
      const int oabs = o0 + oth;
      const float* wrow = p.tWih + (size_t)oabs * 1536;
      const float* whh  = p.tWhh + (size_t)oabs * 64;
      const int k0 = kth * 200;
      float tacc[4] = {0.f, 0.f, 0.f, 0.f};
      #pragma unroll 2
      for (int kf = 0; kf < 50; ++kf) {
        const int k = k0 + kf * 4;
        const float* wsrc = (k < 1536) ? (wrow + k) : (whh + (k - 1536));
        float4 wv = *(const float4*)wsrc;
        #pragma unroll
        for (int bi = 0; bi < 4; ++bi) {
          const int r = bi * 4 + bth4;
          const float* os = (k < 1536) ? &opAll[r][k] : &th2s[r][k - 1536];
          float4 ov = *(const float4*)os;
          tacc[bi] += wv.x*ov.x + wv.y*ov.y + wv.z*ov.z + wv.w*ov.w;
        }
      }
      #pragma unroll
      for (int bi = 0; bi < 4; ++bi) accT[kth][oth][bi * 4 + bth4] = tacc[bi];
    }
    __syncthreads();
    if (t < 128) {                        // tg: 8 outs x 16 b, coherent
      const int o = t & 7, bl = t >> 3;
      float s = 0.f;
      #pragma unroll
      for (int kt = 0; kt < 8; ++kt) s += accT[kt][o][bl];
      cohStore(p.tg + (size_t)(b0 + bl) * 256 + o0 + o, s);
    }
    gsync(p.bm, ++gen, w);

    // ---- Seg2: cl/cr/buf prefetch + th2/tc update + x@W + gates + store
    float clv = 0.f, crv = 0.f, bhv = 0.f, bcv = 0.f;
    if (t < 256) {
      const int n = t & 15, bl = t >> 4, na = nc0 + n;
      clv = cohLoad(p.stack + ((size_t)(b0 + bl) * SROWS + sp1t[step][bl]) * 1024 + 512 + na);
      crv = cohLoad(p.stack + ((size_t)(b0 + bl) * SROWS + sp2t[step][bl]) * 1024 + 512 + na);
      int bx = buft[step][bl];
      if (bx < LL) {
        bhv = p.seq[((size_t)(b0 + bl) * LL + bx) * 1024 + na];
        bcv = p.seq[((size_t)(b0 + bl) * LL + bx) * 1024 + 512 + na];
      }
    }
    #pragma unroll
    for (int rep = 0; rep < 2; ++rep) {    // tracking LSTM elementwise, 16b x 64j
      const int it = t + rep * 512;
      const int b = it >> 6, j = it & 63;
      const float* tgb = p.tg + (size_t)(b0 + b) * 256;
      float gi = cohLoad(tgb + j)        + tbsum[j];
      float gf = cohLoad(tgb + 64 + j)   + tbsum[64 + j];
      float gg = cohLoad(tgb + 128 + j)  + tbsum[128 + j];
      float go = cohLoad(tgb + 192 + j)  + tbsum[192 + j];
      float c2 = sigm(gf) * tc2s[b][j] + sigm(gi) * tanh_f(gg);
      float h2 = sigm(go) * tanh_f(c2);
      tc2s[b][j] = c2;
      th2s[b][j] = h2;
    }
    __syncthreads();
    if (anyred) {                          // x@W: 64 cols x 16 b, K=64
      #pragma unroll
      for (int rep = 0; rep < 2; ++rep) {
        const int it = t + rep * 512;
        const int c = it >> 4, b = it & 15;
        float x = 0.f;
        #pragma unroll 4
        for (int j4 = 0; j4 < 64; j4 += 4) {
          float4 xv = *(const float4*)&th2s[b][j4];
          float4 wv = *(const float4*)&wXs[c][j4];
          x += xv.x*wv.x + xv.y*wv.y + xv.z*wv.z + xv.w*wv.w;
        }
        xS[c][b] = x;
      }
      __syncthreads();
    }
    if (t < 256) {
      const int n = t & 15, bl = t >> 4, na = nc0 + n;
      float h, c;
      if (redt[step][bl]) {
        float pre[4];
        #pragma unroll
        for (int g = 0; g < 4; ++g) {
          const int cc = g * 16 + n;
          pre[g] = accS[0][cc][bl] + accS[1][cc][bl] + accS[2][cc][bl]
                 + accS[3][cc][bl] + xS[cc][bl] + biasS[g][n];
        }
        float iv = sigm(pre[0]), ov = sigm(pre[1]);
        float fv = sigm(pre[2]), uv = tanh_f(pre[3]);
        c = iv * uv + fv * (clv + crv);
        h = ov * tanh_f(c);
      } else { h = bhv; c = bcv; }
      float* sr = p.stack + ((size_t)(b0 + bl) * SROWS + step) * 1024;
      cohStore(sr + na, h);
      cohStore(sr + 512 + na, c);
      if (step == TT) p.out[(size_t)(b0 + bl) * 512 + na] = h;
    }
    gsync(p.bm, ++gen, w);
  }
}

extern "C" void kernel_launch(void* const* d_in, const int* in_sizes, int n_in,
                              void* d_out, int out_size, void* d_ws, size_t ws_size,
                              hipStream_t stream) {
  Params p;
  p.seq   = (const float*)d_in[0];
  p.trans = (const int*)d_in[1];
  p.Wx[0] = (const float*)d_in[2];   // W_i
  p.Wx[1] = (const float*)d_in[4];   // W_o
  p.Wx[2] = (const float*)d_in[4];   // W_o  (ref bug: f-gate uses W_o)
  p.Wx[3] = (const float*)d_in[5];   // W_u
  p.Ul[0] = (const float*)d_in[6];  p.Ur[0] = (const float*)d_in[7];    // i
  p.Ul[1] = (const float*)d_in[10]; p.Ur[1] = (const float*)d_in[11];   // o
  p.Ul[2] = (const float*)d_in[8];  p.Ur[2] = (const float*)d_in[9];    // f
  p.Ul[3] = (const float*)d_in[12]; p.Ur[3] = (const float*)d_in[13];   // u
  p.bias[0] = (const float*)d_in[14];  // b_i
  p.bias[1] = (const float*)d_in[16];  // b_o
  p.bias[2] = (const float*)d_in[15];  // b_f
  p.bias[3] = (const float*)d_in[17];  // b_u
  p.tWih = (const float*)d_in[18];
  p.tWhh = (const float*)d_in[19];
  p.tbih = (const float*)d_in[20];
  p.tbhh = (const float*)d_in[21];
  p.th0  = (const float*)d_in[22];
  p.tc0  = (const float*)d_in[23];

  float* ws = (float*)d_ws;
  size_t off = 0;
  p.stack = ws + off; off += (size_t)NB * SROWS * 1024;  // 33.5 MB
  p.tg    = ws + off; off += (size_t)NB * 256;
  unsigned* barmem = (unsigned*)(ws + off); off += 512;
  if (off * sizeof(float) > ws_size) return;
  p.bm  = barmem;
  p.out = (float*)d_out;

  hipMemsetAsync(barmem, 0, 512 * sizeof(unsigned), stream);

  void* args[] = { &p };
  hipError_t e = hipLaunchCooperativeKernel((void*)spinn_kernel, dim3(NWG), dim3(NTH),
                                            args, 0, stream);
  if (e != hipSuccess) {
    (void)hipGetLastError();
    spinn_kernel<<<dim3(NWG), dim3(NTH), 0, stream>>>(p);
  }
}